// Round 1
// baseline (335.916 us; speedup 1.0000x reference)
//
#include <hip/hip_runtime.h>

// Problem constants (from reference setup_inputs)
#define BQ     4        // batch
#define GROUPS 8
#define POOL   64
#define TOPK   4
#define CH     96       // D / GROUPS = 768/8
#define LDIM   524288   // 4096*4*32
#define TL     (2*LDIM) // 1048576 floats per pool row / per combined output

// Kernel 1 (one block): cosine sim -> mean -> top-4 -> normalized weights.
// Writes idx (as float) + weights to the tail of d_out, and idx/weights to ws
// for the combine kernel.
__global__ void retr_topk_kernel(const float* __restrict__ q,      // [4,768]
                                 const float* __restrict__ keys,   // [8,64,96] (keys[0])
                                 float* __restrict__ out_tail,     // 8 floats
                                 int*   __restrict__ ws_idx,       // 4 ints
                                 float* __restrict__ ws_w)         // 4 floats
{
    __shared__ float qs[BQ * GROUPS * CH];   // 3072 floats, raw q
    __shared__ float norms[BQ * GROUPS];     // 32 q-norms
    __shared__ float sg[GROUPS * CH];        // sum_b qn[b,g,c]
    __shared__ float idx_sim[POOL];          // 64 mean sims

    const int t = threadIdx.x;

    for (int i = t; i < BQ * GROUPS * CH; i += blockDim.x) qs[i] = q[i];
    __syncthreads();

    // per-(b,g) q norms (32 of them, 96-elem each)
    if (t < BQ * GROUPS) {
        float n2 = 0.f;
        const float* p = &qs[t * CH];
        for (int c = 0; c < CH; ++c) { float v = p[c]; n2 = fmaf(v, v, n2); }
        norms[t] = fmaxf(sqrtf(n2), 1e-8f);   // torch cosine eps clamp
    }
    __syncthreads();

    // sg[g,c] = sum_b q[b,g,c] / norm[b,g]
    for (int i = t; i < GROUPS * CH; i += blockDim.x) {
        int g = i / CH, c = i - g * CH;
        float acc = 0.f;
        for (int b = 0; b < BQ; ++b)
            acc += qs[(b * GROUPS + g) * CH + c] / norms[b * GROUPS + g];
        sg[i] = acc;
    }
    __syncthreads();

    // idx_sim[p] = (1/32) * sum_g dot(sg[g,:], keys[g,p,:]) / max(||keys[g,p,:]||, eps)
    if (t < POOL) {
        float acc = 0.f;
        for (int g = 0; g < GROUPS; ++g) {
            const float* kp = &keys[(g * POOL + t) * CH];
            float dot = 0.f, n2 = 0.f;
            for (int c = 0; c < CH; ++c) {
                float k = kp[c];
                dot = fmaf(sg[g * CH + c], k, dot);
                n2  = fmaf(k, k, n2);
            }
            acc += dot / fmaxf(sqrtf(n2), 1e-8f);
        }
        idx_sim[t] = acc * (1.0f / (BQ * GROUPS));
    }
    __syncthreads();

    // top-4, descending, lowest-index tie-break (matches jax.lax.top_k)
    if (t == 0) {
        unsigned long long used = 0ULL;
        int   idx[TOPK];
        float val[TOPK];
        float sum = 0.f;
        for (int k = 0; k < TOPK; ++k) {
            float best = -3.0e38f; int bi = 0;
            for (int p = 0; p < POOL; ++p) {
                if ((used >> p) & 1ULL) continue;
                if (idx_sim[p] > best) { best = idx_sim[p]; bi = p; }
            }
            used |= (1ULL << bi);
            idx[k] = bi; val[k] = best; sum += best;
        }
        float inv = 1.0f / (sum + 1e-9f);
        for (int k = 0; k < TOPK; ++k) {
            float w = val[k] * inv;
            ws_idx[k] = idx[k];
            ws_w[k]   = w;
            out_tail[k]        = (float)idx[k];  // idx_vote as fp32 (exact ints)
            out_tail[TOPK + k] = w;              // dis_weight
        }
    }
}

// Kernel 2: combined[i] = sum_k w[k] * woc[idx[k]][i], broadcast-stored to 4 batches.
// float4 per thread: 64 B read + 64 B written per thread, fully coalesced.
__global__ void retr_combine_kernel(const float* __restrict__ woc,  // [64, 2*L]
                                    const int*   __restrict__ ws_idx,
                                    const float* __restrict__ ws_w,
                                    float*       __restrict__ out)  // [4, 2*L]
{
    const int i = blockIdx.x * blockDim.x + threadIdx.x;  // float4 index over TL/4

    const int   i0 = ws_idx[0], i1 = ws_idx[1], i2 = ws_idx[2], i3 = ws_idx[3];
    const float w0 = ws_w[0],  w1 = ws_w[1],  w2 = ws_w[2],  w3 = ws_w[3];

    const float4* r0 = (const float4*)(woc + (size_t)i0 * TL);
    const float4* r1 = (const float4*)(woc + (size_t)i1 * TL);
    const float4* r2 = (const float4*)(woc + (size_t)i2 * TL);
    const float4* r3 = (const float4*)(woc + (size_t)i3 * TL);

    float4 a = r0[i], b = r1[i], c = r2[i], d = r3[i];
    float4 o;
    o.x = w0 * a.x + w1 * b.x + w2 * c.x + w3 * d.x;
    o.y = w0 * a.y + w1 * b.y + w2 * c.y + w3 * d.y;
    o.z = w0 * a.z + w1 * b.z + w2 * c.z + w3 * d.z;
    o.w = w0 * a.w + w1 * b.w + w2 * c.w + w3 * d.w;

    float4* ob = (float4*)out;
    const int stride4 = TL / 4;
    ob[i]               = o;
    ob[i + stride4]     = o;
    ob[i + 2 * stride4] = o;
    ob[i + 3 * stride4] = o;
}

extern "C" void kernel_launch(void* const* d_in, const int* in_sizes, int n_in,
                              void* d_out, int out_size, void* d_ws, size_t ws_size,
                              hipStream_t stream) {
    const float* queries = (const float*)d_in[0];  // [4, 768]
    const float* keys    = (const float*)d_in[1];  // [1, 8, 64, 96]
    const float* woc     = (const float*)d_in[2];  // [64, 2, 524288]

    float* out      = (float*)d_out;               // [4*2*L] + 4 idx + 4 w
    float* out_tail = out + (size_t)BQ * TL;

    int*   ws_idx = (int*)d_ws;
    float* ws_w   = (float*)((char*)d_ws + 16);

    retr_topk_kernel<<<1, 256, 0, stream>>>(queries, keys, out_tail, ws_idx, ws_w);

    const int threads = 256;
    const int blocks  = (TL / 4) / threads;  // 1024 blocks
    retr_combine_kernel<<<blocks, threads, 0, stream>>>(woc, ws_idx, ws_w, out);
}

// Round 2
// 330.920 us; speedup vs baseline: 1.0151x; 1.0151x over previous
//
#include <hip/hip_runtime.h>

// Problem constants (from reference setup_inputs)
#define BQ     4        // batch
#define GROUPS 8
#define POOL   64
#define TOPK   4
#define CH     96       // D / GROUPS = 768/8
#define LDIM   524288   // 4096*4*32
#define TL     (2*LDIM) // 1048576 floats per pool row / per combined output

// Kernel 1 (one block): cosine sim -> mean -> top-4 -> normalized weights.
__global__ __launch_bounds__(256) void retr_topk_kernel(
        const float* __restrict__ q,      // [4,768] = [b,g,c]
        const float* __restrict__ keys,   // [8,64,96] (keys[0])
        float* __restrict__ out_tail,     // 8 floats (idx as fp32, then weights)
        int*   __restrict__ ws_idx,       // 4 ints
        float* __restrict__ ws_w)         // 4 floats
{
    __shared__ float qs[BQ * GROUPS * CH];   // 3072 floats
    __shared__ float norms[BQ * GROUPS];     // 32 q-norms
    __shared__ float sg[GROUPS * CH];        // sum_b qn[b,g,c]
    __shared__ float idx_sim[POOL];          // 64 mean sims

    const int t = threadIdx.x;

    // stage q via float4 (3072 floats = 768 float4, 256 threads x 3)
    {
        const float4* q4 = (const float4*)q;
        float4* qs4 = (float4*)qs;
        for (int i = t; i < (BQ * GROUPS * CH) / 4; i += 256) qs4[i] = q4[i];
    }
    __syncthreads();

    // per-(b,g) q norms (32 of them, 96-elem each)
    if (t < BQ * GROUPS) {
        float n2 = 0.f;
        const float* p = &qs[t * CH];
        #pragma unroll
        for (int c = 0; c < CH; ++c) { float v = p[c]; n2 = fmaf(v, v, n2); }
        norms[t] = fmaxf(sqrtf(n2), 1e-8f);   // torch cosine eps clamp
    }
    __syncthreads();

    // sg[g,c] = sum_b q[b,g,c] / norm[b,g]
    for (int i = t; i < GROUPS * CH; i += 256) {
        int g = i / CH;
        float acc = 0.f;
        #pragma unroll
        for (int b = 0; b < BQ; ++b)
            acc += qs[(b * GROUPS) * CH + i] / norms[b * GROUPS + g];
        sg[i] = acc;
    }
    __syncthreads();

    // idx_sim[p] = (1/32) * sum_g dot(sg[g,:], keys[g,p,:]) / max(||keys[g,p,:]||, eps)
    // keys rows are 96 floats = 384 B (16B-aligned) -> float4 loads
    if (t < POOL) {
        float acc = 0.f;
        for (int g = 0; g < GROUPS; ++g) {
            const float4* kp4 = (const float4*)(keys + (size_t)(g * POOL + t) * CH);
            const float*  sgp = &sg[g * CH];
            float dot = 0.f, n2 = 0.f;
            #pragma unroll
            for (int j = 0; j < CH / 4; ++j) {
                float4 k = kp4[j];
                dot = fmaf(sgp[4*j+0], k.x, dot);
                dot = fmaf(sgp[4*j+1], k.y, dot);
                dot = fmaf(sgp[4*j+2], k.z, dot);
                dot = fmaf(sgp[4*j+3], k.w, dot);
                n2  = fmaf(k.x, k.x, n2);
                n2  = fmaf(k.y, k.y, n2);
                n2  = fmaf(k.z, k.z, n2);
                n2  = fmaf(k.w, k.w, n2);
            }
            acc += dot / fmaxf(sqrtf(n2), 1e-8f);
        }
        idx_sim[t] = acc * (1.0f / (BQ * GROUPS));
    }
    __syncthreads();

    // top-4, descending, lowest-index tie-break (matches jax.lax.top_k)
    if (t == 0) {
        unsigned long long used = 0ULL;
        int   idx[TOPK];
        float val[TOPK];
        float sum = 0.f;
        for (int k = 0; k < TOPK; ++k) {
            float best = -3.0e38f; int bi = 0;
            for (int p = 0; p < POOL; ++p) {
                if ((used >> p) & 1ULL) continue;
                if (idx_sim[p] > best) { best = idx_sim[p]; bi = p; }
            }
            used |= (1ULL << bi);
            idx[k] = bi; val[k] = best; sum += best;
        }
        float inv = 1.0f / (sum + 1e-9f);
        for (int k = 0; k < TOPK; ++k) {
            float w = val[k] * inv;
            ws_idx[k] = idx[k];
            ws_w[k]   = w;
            out_tail[k]        = (float)idx[k];  // idx_vote as fp32 (exact ints)
            out_tail[TOPK + k] = w;              // dis_weight
        }
    }
}

// Kernel 2: combined[i] = sum_k w[k] * woc[idx[k]][i], broadcast-stored to 4 batches.
// float4 per thread: 64 B read + 64 B write per thread, fully coalesced.
__global__ __launch_bounds__(256) void retr_combine_kernel(
        const float* __restrict__ woc,  // [64, 2*L]
        const int*   __restrict__ ws_idx,
        const float* __restrict__ ws_w,
        float*       __restrict__ out)  // [4, 2*L]
{
    const int i = blockIdx.x * blockDim.x + threadIdx.x;  // float4 index over TL/4

    const int   i0 = ws_idx[0], i1 = ws_idx[1], i2 = ws_idx[2], i3 = ws_idx[3];
    const float w0 = ws_w[0],  w1 = ws_w[1],  w2 = ws_w[2],  w3 = ws_w[3];

    const float4* r0 = (const float4*)(woc + (size_t)i0 * TL);
    const float4* r1 = (const float4*)(woc + (size_t)i1 * TL);
    const float4* r2 = (const float4*)(woc + (size_t)i2 * TL);
    const float4* r3 = (const float4*)(woc + (size_t)i3 * TL);

    float4 a = r0[i], b = r1[i], c = r2[i], d = r3[i];
    float4 o;
    o.x = w0 * a.x + w1 * b.x + w2 * c.x + w3 * d.x;
    o.y = w0 * a.y + w1 * b.y + w2 * c.y + w3 * d.y;
    o.z = w0 * a.z + w1 * b.z + w2 * c.z + w3 * d.z;
    o.w = w0 * a.w + w1 * b.w + w2 * c.w + w3 * d.w;

    float4* ob = (float4*)out;
    const int stride4 = TL / 4;
    ob[i]               = o;
    ob[i + stride4]     = o;
    ob[i + 2 * stride4] = o;
    ob[i + 3 * stride4] = o;
}

extern "C" void kernel_launch(void* const* d_in, const int* in_sizes, int n_in,
                              void* d_out, int out_size, void* d_ws, size_t ws_size,
                              hipStream_t stream) {
    const float* queries = (const float*)d_in[0];  // [4, 768]
    const float* keys    = (const float*)d_in[1];  // [1, 8, 64, 96]
    const float* woc     = (const float*)d_in[2];  // [64, 2, 524288]

    float* out      = (float*)d_out;               // [4*2*L] + 4 idx + 4 w
    float* out_tail = out + (size_t)BQ * TL;

    int*   ws_idx = (int*)d_ws;
    float* ws_w   = (float*)((char*)d_ws + 16);

    retr_topk_kernel<<<1, 256, 0, stream>>>(queries, keys, out_tail, ws_idx, ws_w);

    const int threads = 256;
    const int blocks  = (TL / 4) / threads;  // 1024 blocks
    retr_combine_kernel<<<blocks, threads, 0, stream>>>(woc, ws_idx, ws_w, out);
}